// Round 1
// baseline (857.290 us; speedup 1.0000x reference)
//
#include <hip/hip_runtime.h>
#include <math.h>

#define N_NODES 50000
#define E_EDGES 800000
#define E2      (E_EDGES + N_NODES)   // 850000 with self loops
#define F_INDIM 256
#define H_DIM   64
#define K_DIM   32
#define NEG_SLOPE 0.2f

// ---- ordered-int encoding of float for atomicMax on signed int ----
__device__ __forceinline__ int enc_f(float f) {
    int i = __float_as_int(f);
    return i >= 0 ? i : (i ^ 0x7FFFFFFF);
}
__device__ __forceinline__ float dec_f(int e) {
    int i = e >= 0 ? e : (e ^ 0x7FFFFFFF);
    return __int_as_float(i);
}

__global__ void fillint_kernel(int* __restrict__ p, int v, int n) {
    int i = blockIdx.x * blockDim.x + threadIdx.x;
    if (i < n) p[i] = v;
}

// ---- xl = X@Wl1, xr = X@Wr1 fused.  16 nodes x 128 outputs per block ----
__global__ __launch_bounds__(256) void gemm1_kernel(
        const float* __restrict__ X, const float* __restrict__ Wl,
        const float* __restrict__ Wr, float* __restrict__ xl, float* __restrict__ xr) {
    __shared__ float xs[16][F_INDIM];          // 16 KB
    const int m0 = blockIdx.x * 16;
    const int tid = threadIdx.x;
    const float* src = X + (size_t)m0 * F_INDIM;
    for (int i = tid; i < 16 * F_INDIM; i += 256)
        xs[i >> 8][i & 255] = src[i];
    __syncthreads();
    const int tx = tid & 127;                  // output col 0..127
    const int ty = tid >> 7;                   // 0..1
    const float* W = (tx < H_DIM) ? Wl : Wr;
    const int col = tx & 63;
    float acc[8];
#pragma unroll
    for (int i = 0; i < 8; ++i) acc[i] = 0.f;
    for (int k = 0; k < F_INDIM; ++k) {
        float wv = W[k * H_DIM + col];
#pragma unroll
        for (int i = 0; i < 8; ++i) acc[i] += xs[ty + 2 * i][k] * wv;
    }
    float* out = (tx < H_DIM) ? xl : xr;
#pragma unroll
    for (int i = 0; i < 8; ++i)
        out[(size_t)(m0 + ty + 2 * i) * H_DIM + col] = acc[i];
}

// ---- layer1 edge score: one 64-lane wave per edge ----
__global__ __launch_bounds__(256) void escore64_kernel(
        const int* __restrict__ ei0, const int* __restrict__ ei1,
        const float* __restrict__ xl, const float* __restrict__ xr,
        const float* __restrict__ att, float* __restrict__ s, int* __restrict__ smax) {
    const int wid  = (blockIdx.x * 256 + threadIdx.x) >> 6;
    const int lane = threadIdx.x & 63;
    if (wid >= E2) return;
    int srcn, dstn;
    if (wid < E_EDGES) { srcn = ei0[wid]; dstn = ei1[wid]; }
    else               { srcn = dstn = wid - E_EDGES; }
    float a = xl[(size_t)srcn * H_DIM + lane] + xr[(size_t)dstn * H_DIM + lane];
    a = a > 0.f ? a : NEG_SLOPE * a;
    float v = a * att[lane];
#pragma unroll
    for (int m = 32; m >= 1; m >>= 1) v += __shfl_xor(v, m, 64);
    if (lane == 0) { s[wid] = v; atomicMax(&smax[dstn], enc_f(v)); }
}

// ---- exp + denom (shared by both layers); overwrites s with ex in place ----
__global__ __launch_bounds__(256) void eexp_kernel(
        const int* __restrict__ ei1, float* __restrict__ s,
        const int* __restrict__ smax, float* __restrict__ den) {
    const int e = blockIdx.x * 256 + threadIdx.x;
    if (e >= E2) return;
    const int dstn = (e < E_EDGES) ? ei1[e] : (e - E_EDGES);
    float v = expf(s[e] - dec_f(smax[dstn]));
    s[e] = v;
    atomicAdd(&den[dstn], v);
}

// ---- layer1 scatter: out[dst] += alpha * xl[src], wave per edge ----
__global__ __launch_bounds__(256) void escatter64_kernel(
        const int* __restrict__ ei0, const int* __restrict__ ei1,
        const float* __restrict__ xl, const float* __restrict__ ex,
        const float* __restrict__ den, float* __restrict__ out) {
    const int wid  = (blockIdx.x * 256 + threadIdx.x) >> 6;
    const int lane = threadIdx.x & 63;
    if (wid >= E2) return;
    int srcn, dstn;
    if (wid < E_EDGES) { srcn = ei0[wid]; dstn = ei1[wid]; }
    else               { srcn = dstn = wid - E_EDGES; }
    const float alpha = ex[wid] / (den[dstn] + 1e-16f);
    atomicAdd(&out[(size_t)dstn * H_DIM + lane],
              alpha * xl[(size_t)srcn * H_DIM + lane]);
}

// ---- h = elu(acc+b1); xl2 = h@Wl2, xr2 = h@Wr2.  One wave per node ----
__global__ __launch_bounds__(256) void hgemm2_kernel(
        const float* __restrict__ acc1, const float* __restrict__ b1,
        const float* __restrict__ Wl2, const float* __restrict__ Wr2,
        float* __restrict__ xl2, float* __restrict__ xr2) {
    __shared__ float hs[4][H_DIM];
    const int wIdx = threadIdx.x >> 6;
    const int lane = threadIdx.x & 63;
    const int n = blockIdx.x * 4 + wIdx;
    float hv = acc1[(size_t)n * H_DIM + lane] + b1[lane];
    hv = hv > 0.f ? hv : expm1f(hv);
    hs[wIdx][lane] = hv;
    __syncthreads();
    const float* W = (lane < K_DIM) ? Wl2 : Wr2;
    const int col = lane & 31;
    float acc = 0.f;
#pragma unroll
    for (int k = 0; k < H_DIM; ++k) acc += hs[wIdx][k] * W[k * K_DIM + col];
    float* out = (lane < K_DIM) ? xl2 : xr2;
    out[(size_t)n * K_DIM + col] = acc;
}

// ---- layer2 edge score: half-wave (32 lanes) per edge ----
__global__ __launch_bounds__(256) void escore32_kernel(
        const int* __restrict__ ei0, const int* __restrict__ ei1,
        const float* __restrict__ xl, const float* __restrict__ xr,
        const float* __restrict__ att, float* __restrict__ s, int* __restrict__ smax) {
    const int t = blockIdx.x * 256 + threadIdx.x;
    const int e = t >> 5;
    const int sub = t & 31;
    if (e >= E2) return;
    int srcn, dstn;
    if (e < E_EDGES) { srcn = ei0[e]; dstn = ei1[e]; }
    else             { srcn = dstn = e - E_EDGES; }
    float a = xl[(size_t)srcn * K_DIM + sub] + xr[(size_t)dstn * K_DIM + sub];
    a = a > 0.f ? a : NEG_SLOPE * a;
    float v = a * att[sub];
#pragma unroll
    for (int m = 16; m >= 1; m >>= 1) v += __shfl_xor(v, m, 64);
    if (sub == 0) { s[e] = v; atomicMax(&smax[dstn], enc_f(v)); }
}

// ---- layer2 scatter into Z-logit accumulator (in d_out) ----
__global__ __launch_bounds__(256) void escatter32_kernel(
        const int* __restrict__ ei0, const int* __restrict__ ei1,
        const float* __restrict__ xl, const float* __restrict__ ex,
        const float* __restrict__ den, float* __restrict__ out) {
    const int t = blockIdx.x * 256 + threadIdx.x;
    const int e = t >> 5;
    const int sub = t & 31;
    if (e >= E2) return;
    int srcn, dstn;
    if (e < E_EDGES) { srcn = ei0[e]; dstn = ei1[e]; }
    else             { srcn = dstn = e - E_EDGES; }
    const float alpha = ex[e] / (den[dstn] + 1e-16f);
    atomicAdd(&out[(size_t)dstn * K_DIM + sub],
              alpha * xl[(size_t)srcn * K_DIM + sub]);
}

// ---- row softmax over K=32 (2 nodes per wave), in place ----
__global__ __launch_bounds__(256) void softmaxZ_kernel(
        float* __restrict__ Zacc, const float* __restrict__ b2) {
    const int t = blockIdx.x * 256 + threadIdx.x;
    const int n = t >> 5;
    const int sub = t & 31;
    if (n >= N_NODES) return;
    float v = Zacc[(size_t)n * K_DIM + sub] + b2[sub];
    float mx = v;
#pragma unroll
    for (int m = 16; m >= 1; m >>= 1) mx = fmaxf(mx, __shfl_xor(mx, m, 64));
    float e = expf(v - mx);
    float sum = e;
#pragma unroll
    for (int m = 16; m >= 1; m >>= 1) sum += __shfl_xor(sum, m, 64);
    Zacc[(size_t)n * K_DIM + sub] = e / sum;
}

// ---- spatial scatter: Zc[row] += Z[col], half-wave per edge ----
__global__ __launch_bounds__(256) void sscatter_kernel(
        const int* __restrict__ row, const int* __restrict__ col,
        const float* __restrict__ Z, float* __restrict__ Zc) {
    const int t = blockIdx.x * 256 + threadIdx.x;
    const int e = t >> 5;
    const int sub = t & 31;
    if (e >= E_EDGES) return;
    atomicAdd(&Zc[(size_t)row[e] * K_DIM + sub],
              Z[(size_t)col[e] * K_DIM + sub]);
}

// ---- out2 = (Z + w*Zc) @ relu(M); one node per 256-thread block ----
__global__ __launch_bounds__(256) void final_kernel(
        const float* __restrict__ Z, const float* __restrict__ Zc,
        const float* __restrict__ M, const float* __restrict__ edge_w,
        float* __restrict__ out2, float* __restrict__ wout) {
    __shared__ float zs[K_DIM];
    const int n = blockIdx.x;
    const int tid = threadIdx.x;
    const float w = 1.f / (1.f + expf(-edge_w[0]));
    if (tid < K_DIM)
        zs[tid] = Z[(size_t)n * K_DIM + tid] + w * Zc[(size_t)n * K_DIM + tid];
    __syncthreads();
    float acc = 0.f;
#pragma unroll
    for (int k = 0; k < K_DIM; ++k)
        acc += zs[k] * fmaxf(M[k * F_INDIM + tid], 0.f);
    out2[(size_t)n * F_INDIM + tid] = acc;
    if (n == 0 && tid == 0) wout[0] = w;
}

extern "C" void kernel_launch(void* const* d_in, const int* in_sizes, int n_in,
                              void* d_out, int out_size, void* d_ws, size_t ws_size,
                              hipStream_t stream) {
    const float* X    = (const float*)d_in[0];
    const int*   eif  = (const int*)d_in[1];
    const int*   eis  = (const int*)d_in[2];
    const float* Wl1  = (const float*)d_in[3];
    const float* Wr1  = (const float*)d_in[4];
    const float* att1 = (const float*)d_in[5];
    const float* b1   = (const float*)d_in[6];
    const float* Wl2  = (const float*)d_in[7];
    const float* Wr2  = (const float*)d_in[8];
    const float* att2 = (const float*)d_in[9];
    const float* b2   = (const float*)d_in[10];
    const float* M    = (const float*)d_in[11];
    const float* ew   = (const float*)d_in[12];

    const int* ei0 = eif;               // src row
    const int* ei1 = eif + E_EDGES;     // dst row
    const int* sr  = eis;               // spatial row (scatter target)
    const int* sc  = eis + E_EDGES;     // spatial col (gather source)

    const size_t N = N_NODES;
    float* fws = (float*)d_ws;
    size_t off = 0;
    float* xl1  = fws + off; off += N * H_DIM;    // later reused as xl2 (first 32N)
    float* xr1  = fws + off; off += N * H_DIM;    // later reused as xr2
    float* acc1 = fws + off; off += N * H_DIM;    // layer1 output accumulator
    float* se   = fws + off; off += (size_t)E2;   // edge score, then ex (in place)
    int*   smax = (int*)(fws + off); off += N;
    float* den  = fws + off; off += N;
    float* Zc   = fws + off; off += N * K_DIM;
    float* xl2 = xl1;
    float* xr2 = xr1;

    float* Zacc = (float*)d_out;                       // 32N: logits -> Z
    float* out2 = (float*)d_out + N * (size_t)K_DIM;   // 256N
    float* wout = (float*)d_out + N * (size_t)(K_DIM + F_INDIM);

    // ---- layer 1 init ----
    hipMemsetAsync(acc1, 0, N * H_DIM * sizeof(float), stream);
    hipMemsetAsync(den, 0, N * sizeof(float), stream);
    fillint_kernel<<<(N_NODES + 255) / 256, 256, 0, stream>>>(smax, (int)0x80000000, N_NODES);

    gemm1_kernel<<<N_NODES / 16, 256, 0, stream>>>(X, Wl1, Wr1, xl1, xr1);
    escore64_kernel<<<E2 / 4, 256, 0, stream>>>(ei0, ei1, xl1, xr1, att1, se, smax);
    eexp_kernel<<<(E2 + 255) / 256, 256, 0, stream>>>(ei1, se, smax, den);
    escatter64_kernel<<<E2 / 4, 256, 0, stream>>>(ei0, ei1, xl1, se, den, acc1);
    hgemm2_kernel<<<N_NODES / 4, 256, 0, stream>>>(acc1, b1, Wl2, Wr2, xl2, xr2);

    // ---- layer 2 init ----
    hipMemsetAsync(den, 0, N * sizeof(float), stream);
    hipMemsetAsync(Zacc, 0, N * K_DIM * sizeof(float), stream);
    hipMemsetAsync(Zc, 0, N * K_DIM * sizeof(float), stream);
    fillint_kernel<<<(N_NODES + 255) / 256, 256, 0, stream>>>(smax, (int)0x80000000, N_NODES);

    escore32_kernel<<<E2 / 8, 256, 0, stream>>>(ei0, ei1, xl2, xr2, att2, se, smax);
    eexp_kernel<<<(E2 + 255) / 256, 256, 0, stream>>>(ei1, se, smax, den);
    escatter32_kernel<<<E2 / 8, 256, 0, stream>>>(ei0, ei1, xl2, se, den, Zacc);
    softmaxZ_kernel<<<N_NODES * K_DIM / 256, 256, 0, stream>>>(Zacc, b2);
    sscatter_kernel<<<E_EDGES / 8, 256, 0, stream>>>(sr, sc, Zacc, Zc);
    final_kernel<<<N_NODES, 256, 0, stream>>>(Zacc, Zc, M, ew, out2, wout);
}

// Round 2
// 579.580 us; speedup vs baseline: 1.4792x; 1.4792x over previous
//
#include <hip/hip_runtime.h>
#include <math.h>

#define N_NODES 50000
#define E_EDGES 800000
#define F_INDIM 256
#define H_DIM   64
#define K_DIM   32
#define NEG_SLOPE 0.2f
#define SCAN_BLOCKS 196          // 196*256 = 50176 >= 50000

// ---- xl = X@Wl1, xr = X@Wr1 fused.  16 nodes x 128 outputs per block ----
__global__ __launch_bounds__(256) void gemm1_kernel(
        const float* __restrict__ X, const float* __restrict__ Wl,
        const float* __restrict__ Wr, float* __restrict__ xl, float* __restrict__ xr) {
    __shared__ float xs[16][F_INDIM];          // 16 KB
    const int m0 = blockIdx.x * 16;
    const int tid = threadIdx.x;
    const float* src = X + (size_t)m0 * F_INDIM;
    for (int i = tid; i < 16 * F_INDIM; i += 256)
        xs[i >> 8][i & 255] = src[i];
    __syncthreads();
    const int tx = tid & 127;                  // output col 0..127
    const int ty = tid >> 7;                   // 0..1
    const float* W = (tx < H_DIM) ? Wl : Wr;
    const int col = tx & 63;
    float acc[8];
#pragma unroll
    for (int i = 0; i < 8; ++i) acc[i] = 0.f;
    for (int k = 0; k < F_INDIM; ++k) {
        float wv = W[k * H_DIM + col];
#pragma unroll
        for (int i = 0; i < 8; ++i) acc[i] += xs[ty + 2 * i][k] * wv;
    }
    float* out = (tx < H_DIM) ? xl : xr;
#pragma unroll
    for (int i = 0; i < 8; ++i)
        out[(size_t)(m0 + ty + 2 * i) * H_DIM + col] = acc[i];
}

// ---- degree histograms for both graphs in one pass ----
__global__ __launch_bounds__(256) void hist_kernel(
        const int* __restrict__ dstF, const int* __restrict__ rowS,
        int* __restrict__ degF, int* __restrict__ degS) {
    int e = blockIdx.x * 256 + threadIdx.x;
    if (e >= E_EDGES) return;
    atomicAdd(&degF[dstF[e]], 1);
    atomicAdd(&degS[rowS[e]], 1);
}

// ---- scan stage 1: per-block sums ----
__global__ __launch_bounds__(256) void scan1_kernel(
        const int* __restrict__ degF, const int* __restrict__ degS,
        int* __restrict__ bsF, int* __restrict__ bsS) {
    __shared__ int sF[256], sS[256];
    const int tid = threadIdx.x;
    const int i = blockIdx.x * 256 + tid;
    sF[tid] = (i < N_NODES) ? degF[i] : 0;
    sS[tid] = (i < N_NODES) ? degS[i] : 0;
    __syncthreads();
    for (int s = 128; s > 0; s >>= 1) {
        if (tid < s) { sF[tid] += sF[tid + s]; sS[tid] += sS[tid + s]; }
        __syncthreads();
    }
    if (tid == 0) { bsF[blockIdx.x] = sF[0]; bsS[blockIdx.x] = sS[0]; }
}

// ---- scan stage 2: serial exclusive scan of block sums (196 values) ----
__global__ void scan2_kernel(int* __restrict__ bsF, int* __restrict__ bsS) {
    if (threadIdx.x == 0) {
        int run = 0;
        for (int j = 0; j < SCAN_BLOCKS; ++j) { int t = bsF[j]; bsF[j] = run; run += t; }
    } else if (threadIdx.x == 1) {
        int run = 0;
        for (int j = 0; j < SCAN_BLOCKS; ++j) { int t = bsS[j]; bsS[j] = run; run += t; }
    }
}

// ---- scan stage 3: per-block exclusive scan + base; writes offsets & cursors ----
__global__ __launch_bounds__(256) void scan3_kernel(
        const int* __restrict__ degF, const int* __restrict__ degS,
        const int* __restrict__ bsF, const int* __restrict__ bsS,
        int* __restrict__ offF, int* __restrict__ offS,
        int* __restrict__ curF, int* __restrict__ curS) {
    __shared__ int sF[256], sS[256];
    const int tid = threadIdx.x;
    const int i = blockIdx.x * 256 + tid;
    const int vF = (i < N_NODES) ? degF[i] : 0;
    const int vS = (i < N_NODES) ? degS[i] : 0;
    sF[tid] = vF; sS[tid] = vS;
    __syncthreads();
    for (int d = 1; d < 256; d <<= 1) {
        int aF = (tid >= d) ? sF[tid - d] : 0;
        int aS = (tid >= d) ? sS[tid - d] : 0;
        __syncthreads();
        sF[tid] += aF; sS[tid] += aS;
        __syncthreads();
    }
    if (i < N_NODES) {
        int oF = bsF[blockIdx.x] + sF[tid] - vF;   // exclusive
        int oS = bsS[blockIdx.x] + sS[tid] - vS;
        offF[i] = oF; curF[i] = oF;
        offS[i] = oS; curS[i] = oS;
    }
    if (i == N_NODES - 1) { offF[N_NODES] = E_EDGES; offS[N_NODES] = E_EDGES; }
}

// ---- CSR fill via cursors ----
__global__ __launch_bounds__(256) void fill_kernel(
        const int* __restrict__ srcF, const int* __restrict__ dstF,
        const int* __restrict__ colS, const int* __restrict__ rowS,
        int* __restrict__ curF, int* __restrict__ curS,
        int* __restrict__ csrF, int* __restrict__ csrS) {
    int e = blockIdx.x * 256 + threadIdx.x;
    if (e >= E_EDGES) return;
    int p = atomicAdd(&curF[dstF[e]], 1);
    csrF[p] = srcF[e];
    int q = atomicAdd(&curS[rowS[e]], 1);
    csrS[q] = colS[e];
}

// ---- layer1: per-node online-softmax aggregation + ELU + h@[Wl2|Wr2] ----
// one 64-lane wave per node, 4 nodes per block
__global__ __launch_bounds__(256) void agg1_kernel(
        const int* __restrict__ offF, const int* __restrict__ csrF,
        const float* __restrict__ xl, const float* __restrict__ xr,
        const float* __restrict__ att1, const float* __restrict__ b1,
        const float* __restrict__ Wl2, const float* __restrict__ Wr2,
        float* __restrict__ xl2, float* __restrict__ xr2) {
    __shared__ float hs[4][H_DIM];
    const int wid  = threadIdx.x >> 6;
    const int lane = threadIdx.x & 63;
    const int n = blockIdx.x * 4 + wid;
    const float xrv  = xr[(size_t)n * H_DIM + lane];
    const float attv = att1[lane];
    const int start = offF[n], end = offF[n + 1];
    float m = -1e30f, den = 0.f, acc = 0.f;
    // iterations i in [start, end]; i==end is the self loop (src = n)
    int src0 = (start < end) ? csrF[start] : n;
    float x = xl[(size_t)src0 * H_DIM + lane];
    for (int i = start; i <= end; ++i) {
        const float xc = x;
        const int nx = i + 1;
        if (nx <= end) {                        // prefetch next message
            int s2 = (nx < end) ? csrF[nx] : n;
            x = xl[(size_t)s2 * H_DIM + lane];
        }
        float a = xc + xrv;
        a = a > 0.f ? a : NEG_SLOPE * a;
        float v = a * attv;
#pragma unroll
        for (int mm = 32; mm >= 1; mm >>= 1) v += __shfl_xor(v, mm, 64);
        const float mn = fmaxf(m, v);
        const float sc = __expf(m - mn);        // 0 on first iter (m=-1e30)
        const float p  = __expf(v - mn);
        acc = acc * sc + p * xc;
        den = den * sc + p;
        m = mn;
    }
    float h = acc / den + b1[lane];
    h = h > 0.f ? h : expm1f(h);                // ELU
    hs[wid][lane] = h;
    __syncthreads();
    const float* W = (lane < K_DIM) ? Wl2 : Wr2;
    const int col = lane & 31;
    float s = 0.f;
#pragma unroll
    for (int k = 0; k < H_DIM; ++k) s += hs[wid][k] * W[k * K_DIM + col];
    float* o = (lane < K_DIM) ? xl2 : xr2;
    o[(size_t)n * K_DIM + col] = s;
}

// ---- layer2: per-node online-softmax aggregation + bias + row softmax -> Z ----
// half-wave (32 lanes) per node
__global__ __launch_bounds__(256) void agg2_kernel(
        const int* __restrict__ offF, const int* __restrict__ csrF,
        const float* __restrict__ xl2, const float* __restrict__ xr2,
        const float* __restrict__ att2, const float* __restrict__ b2,
        float* __restrict__ Z) {
    const int t = blockIdx.x * 256 + threadIdx.x;
    const int n = t >> 5;
    const int sub = t & 31;
    if (n >= N_NODES) return;
    const float xrv  = xr2[(size_t)n * K_DIM + sub];
    const float attv = att2[sub];
    const int start = offF[n], end = offF[n + 1];
    float m = -1e30f, den = 0.f, acc = 0.f;
    int src0 = (start < end) ? csrF[start] : n;
    float x = xl2[(size_t)src0 * K_DIM + sub];
    for (int i = start; i <= end; ++i) {
        const float xc = x;
        const int nx = i + 1;
        if (nx <= end) {
            int s2 = (nx < end) ? csrF[nx] : n;
            x = xl2[(size_t)s2 * K_DIM + sub];
        }
        float a = xc + xrv;
        a = a > 0.f ? a : NEG_SLOPE * a;
        float v = a * attv;
#pragma unroll
        for (int mm = 16; mm >= 1; mm >>= 1) v += __shfl_xor(v, mm, 64);
        const float mn = fmaxf(m, v);
        const float sc = __expf(m - mn);
        const float p  = __expf(v - mn);
        acc = acc * sc + p * xc;
        den = den * sc + p;
        m = mn;
    }
    float z = acc / den + b2[sub];
    // row softmax over K=32 (stays within the 32-lane half)
    float mx = z;
#pragma unroll
    for (int mm = 16; mm >= 1; mm >>= 1) mx = fmaxf(mx, __shfl_xor(mx, mm, 64));
    float e = __expf(z - mx);
    float ssum = e;
#pragma unroll
    for (int mm = 16; mm >= 1; mm >>= 1) ssum += __shfl_xor(ssum, mm, 64);
    Z[(size_t)n * K_DIM + sub] = e / ssum;
}

// ---- spatial contamination (gather side): Zc[n] = sum_{e: row=n} Z[col_e] ----
__global__ __launch_bounds__(256) void sagg_kernel(
        const int* __restrict__ offS, const int* __restrict__ csrS,
        const float* __restrict__ Z, float* __restrict__ Zc) {
    const int t = blockIdx.x * 256 + threadIdx.x;
    const int n = t >> 5;
    const int sub = t & 31;
    if (n >= N_NODES) return;
    const int start = offS[n], end = offS[n + 1];
    float acc = 0.f;
    if (start < end) {
        int c0 = csrS[start];
        float x = Z[(size_t)c0 * K_DIM + sub];
        for (int i = start; i < end; ++i) {
            const float xc = x;
            if (i + 1 < end) {
                int c2 = csrS[i + 1];
                x = Z[(size_t)c2 * K_DIM + sub];
            }
            acc += xc;
        }
    }
    Zc[(size_t)n * K_DIM + sub] = acc;
}

// ---- out2 = (Z + w*Zc) @ relu(M); one node per 256-thread block ----
__global__ __launch_bounds__(256) void final_kernel(
        const float* __restrict__ Z, const float* __restrict__ Zc,
        const float* __restrict__ M, const float* __restrict__ edge_w,
        float* __restrict__ out2, float* __restrict__ wout) {
    __shared__ float zs[K_DIM];
    const int n = blockIdx.x;
    const int tid = threadIdx.x;
    const float w = 1.f / (1.f + __expf(-edge_w[0]));
    if (tid < K_DIM)
        zs[tid] = Z[(size_t)n * K_DIM + tid] + w * Zc[(size_t)n * K_DIM + tid];
    __syncthreads();
    float acc = 0.f;
#pragma unroll
    for (int k = 0; k < K_DIM; ++k)
        acc += zs[k] * fmaxf(M[k * F_INDIM + tid], 0.f);
    out2[(size_t)n * F_INDIM + tid] = acc;
    if (n == 0 && tid == 0) wout[0] = w;
}

extern "C" void kernel_launch(void* const* d_in, const int* in_sizes, int n_in,
                              void* d_out, int out_size, void* d_ws, size_t ws_size,
                              hipStream_t stream) {
    const float* X    = (const float*)d_in[0];
    const int*   eif  = (const int*)d_in[1];
    const int*   eis  = (const int*)d_in[2];
    const float* Wl1  = (const float*)d_in[3];
    const float* Wr1  = (const float*)d_in[4];
    const float* att1 = (const float*)d_in[5];
    const float* b1   = (const float*)d_in[6];
    const float* Wl2  = (const float*)d_in[7];
    const float* Wr2  = (const float*)d_in[8];
    const float* att2 = (const float*)d_in[9];
    const float* b2   = (const float*)d_in[10];
    const float* M    = (const float*)d_in[11];
    const float* ew   = (const float*)d_in[12];

    const int* srcF = eif;               // feat src
    const int* dstF = eif + E_EDGES;     // feat dst
    const int* rowS = eis;               // spatial row (segment target)
    const int* colS = eis + E_EDGES;     // spatial col (gather source)

    const size_t N = N_NODES;
    char* ws = (char*)d_ws;
    size_t off = 0;
    auto alloc = [&](size_t bytes) { char* p = ws + off; off += (bytes + 255) & ~(size_t)255; return p; };

    float* xl1  = (float*)alloc(N * H_DIM * sizeof(float));
    float* xr1  = (float*)alloc(N * H_DIM * sizeof(float));
    float* xl2  = (float*)alloc(N * K_DIM * sizeof(float));
    float* xr2  = (float*)alloc(N * K_DIM * sizeof(float));
    int*   degF = (int*)alloc(N * sizeof(int));
    int*   degS = (int*)alloc(N * sizeof(int));
    int*   offF = (int*)alloc((N + 1) * sizeof(int));
    int*   offS = (int*)alloc((N + 1) * sizeof(int));
    int*   curF = (int*)alloc(N * sizeof(int));
    int*   curS = (int*)alloc(N * sizeof(int));
    int*   bsF  = (int*)alloc(SCAN_BLOCKS * sizeof(int));
    int*   bsS  = (int*)alloc(SCAN_BLOCKS * sizeof(int));
    int*   csrF = (int*)alloc((size_t)E_EDGES * sizeof(int));
    int*   csrS = (int*)alloc((size_t)E_EDGES * sizeof(int));
    float* Zc   = (float*)alloc(N * K_DIM * sizeof(float));

    float* Z    = (float*)d_out;                          // [N,K]
    float* out2 = (float*)d_out + N * (size_t)K_DIM;      // [N,F]
    float* wout = (float*)d_out + N * (size_t)(K_DIM + F_INDIM);

    // CSR build (degF/degS are adjacent allocations -> one memset would be
    // padding-unsafe; use two, they are tiny)
    hipMemsetAsync(degF, 0, N * sizeof(int), stream);
    hipMemsetAsync(degS, 0, N * sizeof(int), stream);

    gemm1_kernel<<<N_NODES / 16, 256, 0, stream>>>(X, Wl1, Wr1, xl1, xr1);

    hist_kernel<<<(E_EDGES + 255) / 256, 256, 0, stream>>>(dstF, rowS, degF, degS);
    scan1_kernel<<<SCAN_BLOCKS, 256, 0, stream>>>(degF, degS, bsF, bsS);
    scan2_kernel<<<1, 64, 0, stream>>>(bsF, bsS);
    scan3_kernel<<<SCAN_BLOCKS, 256, 0, stream>>>(degF, degS, bsF, bsS, offF, offS, curF, curS);
    fill_kernel<<<(E_EDGES + 255) / 256, 256, 0, stream>>>(srcF, dstF, colS, rowS,
                                                           curF, curS, csrF, csrS);

    agg1_kernel<<<N_NODES / 4, 256, 0, stream>>>(offF, csrF, xl1, xr1, att1, b1,
                                                 Wl2, Wr2, xl2, xr2);
    agg2_kernel<<<(N_NODES * K_DIM + 255) / 256, 256, 0, stream>>>(offF, csrF, xl2, xr2,
                                                                   att2, b2, Z);
    sagg_kernel<<<(N_NODES * K_DIM + 255) / 256, 256, 0, stream>>>(offS, csrS, Z, Zc);
    final_kernel<<<N_NODES, 256, 0, stream>>>(Z, Zc, M, ew, out2, wout);
}

// Round 3
// 455.198 us; speedup vs baseline: 1.8833x; 1.2732x over previous
//
#include <hip/hip_runtime.h>
#include <math.h>

#define N_NODES 50000
#define E_EDGES 800000
#define F_INDIM 256
#define H_DIM   64
#define K_DIM   32
#define NEG_SLOPE 0.2f
#define SCAN_BLOCKS 196          // 196*256 = 50176 >= 50000

// ---- DPP-based partial butterfly helpers (VALU pipe, not DS) ----
// xor1 = quad_perm(1,0,3,2)=0xB1 ; xor2 = quad_perm(2,3,0,1)=0x4E
// xor4-equiv = row_half_mirror(0x141) ; xor8-equiv = row_mirror(0x140)
// (mirror equivalence is valid because prior steps make each sub-group uniform)
template<int CTRL>
__device__ __forceinline__ float dpp_xadd(float v) {
    int x = __builtin_amdgcn_update_dpp(0, __float_as_int(v), CTRL, 0xF, 0xF, true);
    return v + __int_as_float(x);
}
template<int CTRL>
__device__ __forceinline__ float dpp_xmax(float v) {
    int x = __builtin_amdgcn_update_dpp(0, __float_as_int(v), CTRL, 0xF, 0xF, true);
    return fmaxf(v, __int_as_float(x));
}
__device__ __forceinline__ float red_sum64(float v) {
    v = dpp_xadd<0xB1>(v); v = dpp_xadd<0x4E>(v);
    v = dpp_xadd<0x141>(v); v = dpp_xadd<0x140>(v);
    v += __shfl_xor(v, 16, 64);
    v += __shfl_xor(v, 32, 64);
    return v;
}
__device__ __forceinline__ float red_sum32(float v) {
    v = dpp_xadd<0xB1>(v); v = dpp_xadd<0x4E>(v);
    v = dpp_xadd<0x141>(v); v = dpp_xadd<0x140>(v);
    v += __shfl_xor(v, 16, 64);
    return v;
}
__device__ __forceinline__ float red_max32(float v) {
    v = dpp_xmax<0xB1>(v); v = dpp_xmax<0x4E>(v);
    v = dpp_xmax<0x141>(v); v = dpp_xmax<0x140>(v);
    v = fmaxf(v, __shfl_xor(v, 16, 64));
    return v;
}

// ---- xl = X@Wl1, xr = X@Wr1 fused.  16 nodes x 128 outputs per block ----
__global__ __launch_bounds__(256) void gemm1_kernel(
        const float* __restrict__ X, const float* __restrict__ Wl,
        const float* __restrict__ Wr, float* __restrict__ xl, float* __restrict__ xr) {
    __shared__ float xs[16][F_INDIM];          // 16 KB
    const int m0 = blockIdx.x * 16;
    const int tid = threadIdx.x;
    const float* src = X + (size_t)m0 * F_INDIM;
    for (int i = tid; i < 16 * F_INDIM; i += 256)
        xs[i >> 8][i & 255] = src[i];
    __syncthreads();
    const int tx = tid & 127;                  // output col 0..127
    const int ty = tid >> 7;                   // 0..1
    const float* W = (tx < H_DIM) ? Wl : Wr;
    const int col = tx & 63;
    float acc[8];
#pragma unroll
    for (int i = 0; i < 8; ++i) acc[i] = 0.f;
    for (int k = 0; k < F_INDIM; ++k) {
        float wv = W[k * H_DIM + col];
#pragma unroll
        for (int i = 0; i < 8; ++i) acc[i] += xs[ty + 2 * i][k] * wv;
    }
    float* out = (tx < H_DIM) ? xl : xr;
#pragma unroll
    for (int i = 0; i < 8; ++i)
        out[(size_t)(m0 + ty + 2 * i) * H_DIM + col] = acc[i];
}

// ---- degree histograms for both graphs in one pass ----
__global__ __launch_bounds__(256) void hist_kernel(
        const int* __restrict__ dstF, const int* __restrict__ rowS,
        int* __restrict__ degF, int* __restrict__ degS) {
    int e = blockIdx.x * 256 + threadIdx.x;
    if (e >= E_EDGES) return;
    atomicAdd(&degF[dstF[e]], 1);
    atomicAdd(&degS[rowS[e]], 1);
}

// ---- scan stage 1: per-block sums ----
__global__ __launch_bounds__(256) void scan1_kernel(
        const int* __restrict__ degF, const int* __restrict__ degS,
        int* __restrict__ bsF, int* __restrict__ bsS) {
    __shared__ int sF[256], sS[256];
    const int tid = threadIdx.x;
    const int i = blockIdx.x * 256 + tid;
    sF[tid] = (i < N_NODES) ? degF[i] : 0;
    sS[tid] = (i < N_NODES) ? degS[i] : 0;
    __syncthreads();
    for (int s = 128; s > 0; s >>= 1) {
        if (tid < s) { sF[tid] += sF[tid + s]; sS[tid] += sS[tid + s]; }
        __syncthreads();
    }
    if (tid == 0) { bsF[blockIdx.x] = sF[0]; bsS[blockIdx.x] = sS[0]; }
}

// ---- scan stage 2: serial exclusive scan of block sums (196 values) ----
__global__ void scan2_kernel(int* __restrict__ bsF, int* __restrict__ bsS) {
    if (threadIdx.x == 0) {
        int run = 0;
        for (int j = 0; j < SCAN_BLOCKS; ++j) { int t = bsF[j]; bsF[j] = run; run += t; }
    } else if (threadIdx.x == 1) {
        int run = 0;
        for (int j = 0; j < SCAN_BLOCKS; ++j) { int t = bsS[j]; bsS[j] = run; run += t; }
    }
}

// ---- scan stage 3: per-block exclusive scan + base; writes offsets & cursors ----
__global__ __launch_bounds__(256) void scan3_kernel(
        const int* __restrict__ degF, const int* __restrict__ degS,
        const int* __restrict__ bsF, const int* __restrict__ bsS,
        int* __restrict__ offF, int* __restrict__ offS,
        int* __restrict__ curF, int* __restrict__ curS) {
    __shared__ int sF[256], sS[256];
    const int tid = threadIdx.x;
    const int i = blockIdx.x * 256 + tid;
    const int vF = (i < N_NODES) ? degF[i] : 0;
    const int vS = (i < N_NODES) ? degS[i] : 0;
    sF[tid] = vF; sS[tid] = vS;
    __syncthreads();
    for (int d = 1; d < 256; d <<= 1) {
        int aF = (tid >= d) ? sF[tid - d] : 0;
        int aS = (tid >= d) ? sS[tid - d] : 0;
        __syncthreads();
        sF[tid] += aF; sS[tid] += aS;
        __syncthreads();
    }
    if (i < N_NODES) {
        int oF = bsF[blockIdx.x] + sF[tid] - vF;   // exclusive
        int oS = bsS[blockIdx.x] + sS[tid] - vS;
        offF[i] = oF; curF[i] = oF;
        offS[i] = oS; curS[i] = oS;
    }
    if (i == N_NODES - 1) { offF[N_NODES] = E_EDGES; offS[N_NODES] = E_EDGES; }
}

// ---- CSR fill via cursors ----
__global__ __launch_bounds__(256) void fill_kernel(
        const int* __restrict__ srcF, const int* __restrict__ dstF,
        const int* __restrict__ colS, const int* __restrict__ rowS,
        int* __restrict__ curF, int* __restrict__ curS,
        int* __restrict__ csrF, int* __restrict__ csrS) {
    int e = blockIdx.x * 256 + threadIdx.x;
    if (e >= E_EDGES) return;
    int p = atomicAdd(&curF[dstF[e]], 1);
    csrF[p] = srcF[e];
    int q = atomicAdd(&curS[rowS[e]], 1);
    csrS[q] = colS[e];
}

// ---- layer1: per-node online-softmax aggregation + ELU + h@[Wl2|Wr2] ----
// one 64-lane wave per node, 4 nodes per block, 8 edges per iteration
__global__ __launch_bounds__(256) void agg1_kernel(
        const int* __restrict__ offF, const int* __restrict__ csrF,
        const float* __restrict__ xl, const float* __restrict__ xr,
        const float* __restrict__ att1, const float* __restrict__ b1,
        const float* __restrict__ Wl2, const float* __restrict__ Wr2,
        float* __restrict__ xl2, float* __restrict__ xr2) {
    __shared__ float hs[4][H_DIM];
    const int wid  = threadIdx.x >> 6;
    const int lane = threadIdx.x & 63;
    const int n = blockIdx.x * 4 + wid;
    const float xrv  = xr[(size_t)n * H_DIM + lane];
    const float attv = att1[lane];
    // wave-uniform CSR range -> SGPRs, index loads scalarize
    const int start = __builtin_amdgcn_readfirstlane(offF[n]);
    const int endi  = __builtin_amdgcn_readfirstlane(offF[n + 1]);
    const int cnt = endi - start + 1;          // + self loop (message cnt-1 is src=n)
    float m = -1e30f, den = 0.f, acc = 0.f;
    int srcs[8];
#pragma unroll
    for (int j = 0; j < 8; ++j) srcs[j] = (j < cnt - 1) ? csrF[start + j] : n;
    for (int t0 = 0; t0 < cnt; t0 += 8) {
        float xc[8];
#pragma unroll
        for (int j = 0; j < 8; ++j) xc[j] = xl[(size_t)srcs[j] * H_DIM + lane];
        // prefetch next chunk's indices while gathers are in flight
        int nsrcs[8];
#pragma unroll
        for (int j = 0; j < 8; ++j) {
            int t = t0 + 8 + j;
            nsrcs[j] = (t < cnt - 1) ? csrF[start + t] : n;
        }
        float v[8];
#pragma unroll
        for (int j = 0; j < 8; ++j) {
            float a = xc[j] + xrv;
            a = a > 0.f ? a : NEG_SLOPE * a;
            v[j] = a * attv;
        }
#pragma unroll
        for (int j = 0; j < 8; ++j) v[j] = red_sum64(v[j]);
        float vmax = -1e30f;
#pragma unroll
        for (int j = 0; j < 8; ++j) {
            if (t0 + j >= cnt) v[j] = -1e30f;
            vmax = fmaxf(vmax, v[j]);
        }
        const float mn = fmaxf(m, vmax);
        const float sc = __expf(m - mn);       // underflows to 0 on first chunk
        acc *= sc; den *= sc;
#pragma unroll
        for (int j = 0; j < 8; ++j) {
            const float p = __expf(v[j] - mn); // 0 for masked slots
            acc += p * xc[j];
            den += p;
        }
        m = mn;
#pragma unroll
        for (int j = 0; j < 8; ++j) srcs[j] = nsrcs[j];
    }
    float h = acc / den + b1[lane];
    h = h > 0.f ? h : expm1f(h);                // ELU
    hs[wid][lane] = h;
    __syncthreads();
    const float* W = (lane < K_DIM) ? Wl2 : Wr2;
    const int col = lane & 31;
    float s = 0.f;
#pragma unroll
    for (int k = 0; k < H_DIM; ++k) s += hs[wid][k] * W[k * K_DIM + col];
    float* o = (lane < K_DIM) ? xl2 : xr2;
    o[(size_t)n * K_DIM + col] = s;
}

// ---- layer2: per-node online-softmax aggregation + bias + row softmax -> Z ----
// half-wave (32 lanes) per node, 8 edges per iteration
__global__ __launch_bounds__(256) void agg2_kernel(
        const int* __restrict__ offF, const int* __restrict__ csrF,
        const float* __restrict__ xl2, const float* __restrict__ xr2,
        const float* __restrict__ att2, const float* __restrict__ b2,
        float* __restrict__ Z) {
    const int t = blockIdx.x * 256 + threadIdx.x;
    const int n = t >> 5;
    const int sub = t & 31;
    if (n >= N_NODES) return;
    const float xrv  = xr2[(size_t)n * K_DIM + sub];
    const float attv = att2[sub];
    const int start = offF[n], endi = offF[n + 1];
    const int cnt = endi - start + 1;
    float m = -1e30f, den = 0.f, acc = 0.f;
    int srcs[8];
#pragma unroll
    for (int j = 0; j < 8; ++j) srcs[j] = (j < cnt - 1) ? csrF[start + j] : n;
    for (int t0 = 0; t0 < cnt; t0 += 8) {
        float xc[8];
#pragma unroll
        for (int j = 0; j < 8; ++j) xc[j] = xl2[(size_t)srcs[j] * K_DIM + sub];
        int nsrcs[8];
#pragma unroll
        for (int j = 0; j < 8; ++j) {
            int tt = t0 + 8 + j;
            nsrcs[j] = (tt < cnt - 1) ? csrF[start + tt] : n;
        }
        float v[8];
#pragma unroll
        for (int j = 0; j < 8; ++j) {
            float a = xc[j] + xrv;
            a = a > 0.f ? a : NEG_SLOPE * a;
            v[j] = a * attv;
        }
#pragma unroll
        for (int j = 0; j < 8; ++j) v[j] = red_sum32(v[j]);
        float vmax = -1e30f;
#pragma unroll
        for (int j = 0; j < 8; ++j) {
            if (t0 + j >= cnt) v[j] = -1e30f;
            vmax = fmaxf(vmax, v[j]);
        }
        const float mn = fmaxf(m, vmax);
        const float sc = __expf(m - mn);
        acc *= sc; den *= sc;
#pragma unroll
        for (int j = 0; j < 8; ++j) {
            const float p = __expf(v[j] - mn);
            acc += p * xc[j];
            den += p;
        }
        m = mn;
#pragma unroll
        for (int j = 0; j < 8; ++j) srcs[j] = nsrcs[j];
    }
    float z = acc / den + b2[sub];
    // row softmax over K=32 (stays within the 32-lane half)
    float mx = red_max32(z);
    float e = __expf(z - mx);
    float ssum = red_sum32(e);
    Z[(size_t)n * K_DIM + sub] = e / ssum;
}

// ---- spatial contamination (gather side): Zc[n] = sum_{e: row=n} Z[col_e] ----
__global__ __launch_bounds__(256) void sagg_kernel(
        const int* __restrict__ offS, const int* __restrict__ csrS,
        const float* __restrict__ Z, float* __restrict__ Zc) {
    const int t = blockIdx.x * 256 + threadIdx.x;
    const int n = t >> 5;
    const int sub = t & 31;
    if (n >= N_NODES) return;
    const int start = offS[n], endi = offS[n + 1];
    float acc = 0.f;
    for (int t0 = start; t0 < endi; t0 += 8) {
        float val[8];
#pragma unroll
        for (int j = 0; j < 8; ++j) {
            int tt = t0 + j;
            int c = csrS[tt < endi ? tt : (endi - 1)];
            val[j] = Z[(size_t)c * K_DIM + sub];
        }
#pragma unroll
        for (int j = 0; j < 8; ++j)
            acc += (t0 + j < endi) ? val[j] : 0.f;
    }
    Zc[(size_t)n * K_DIM + sub] = acc;
}

// ---- out2 = (Z + w*Zc) @ relu(M); one node per 256-thread block ----
__global__ __launch_bounds__(256) void final_kernel(
        const float* __restrict__ Z, const float* __restrict__ Zc,
        const float* __restrict__ M, const float* __restrict__ edge_w,
        float* __restrict__ out2, float* __restrict__ wout) {
    __shared__ float zs[K_DIM];
    const int n = blockIdx.x;
    const int tid = threadIdx.x;
    const float w = 1.f / (1.f + __expf(-edge_w[0]));
    if (tid < K_DIM)
        zs[tid] = Z[(size_t)n * K_DIM + tid] + w * Zc[(size_t)n * K_DIM + tid];
    __syncthreads();
    float acc = 0.f;
#pragma unroll
    for (int k = 0; k < K_DIM; ++k)
        acc += zs[k] * fmaxf(M[k * F_INDIM + tid], 0.f);
    out2[(size_t)n * F_INDIM + tid] = acc;
    if (n == 0 && tid == 0) wout[0] = w;
}

extern "C" void kernel_launch(void* const* d_in, const int* in_sizes, int n_in,
                              void* d_out, int out_size, void* d_ws, size_t ws_size,
                              hipStream_t stream) {
    const float* X    = (const float*)d_in[0];
    const int*   eif  = (const int*)d_in[1];
    const int*   eis  = (const int*)d_in[2];
    const float* Wl1  = (const float*)d_in[3];
    const float* Wr1  = (const float*)d_in[4];
    const float* att1 = (const float*)d_in[5];
    const float* b1   = (const float*)d_in[6];
    const float* Wl2  = (const float*)d_in[7];
    const float* Wr2  = (const float*)d_in[8];
    const float* att2 = (const float*)d_in[9];
    const float* b2   = (const float*)d_in[10];
    const float* M    = (const float*)d_in[11];
    const float* ew   = (const float*)d_in[12];

    const int* srcF = eif;               // feat src
    const int* dstF = eif + E_EDGES;     // feat dst
    const int* rowS = eis;               // spatial row (segment target)
    const int* colS = eis + E_EDGES;     // spatial col (gather source)

    const size_t N = N_NODES;
    char* ws = (char*)d_ws;
    size_t off = 0;
    auto alloc = [&](size_t bytes) { char* p = ws + off; off += (bytes + 255) & ~(size_t)255; return p; };

    float* xl1  = (float*)alloc(N * H_DIM * sizeof(float));
    float* xr1  = (float*)alloc(N * H_DIM * sizeof(float));
    float* xl2  = (float*)alloc(N * K_DIM * sizeof(float));
    float* xr2  = (float*)alloc(N * K_DIM * sizeof(float));
    int*   degF = (int*)alloc(N * sizeof(int));
    int*   degS = (int*)alloc(N * sizeof(int));
    int*   offF = (int*)alloc((N + 1) * sizeof(int));
    int*   offS = (int*)alloc((N + 1) * sizeof(int));
    int*   curF = (int*)alloc(N * sizeof(int));
    int*   curS = (int*)alloc(N * sizeof(int));
    int*   bsF  = (int*)alloc(SCAN_BLOCKS * sizeof(int));
    int*   bsS  = (int*)alloc(SCAN_BLOCKS * sizeof(int));
    int*   csrF = (int*)alloc((size_t)E_EDGES * sizeof(int));
    int*   csrS = (int*)alloc((size_t)E_EDGES * sizeof(int));
    float* Zc   = (float*)alloc(N * K_DIM * sizeof(float));

    float* Z    = (float*)d_out;                          // [N,K]
    float* out2 = (float*)d_out + N * (size_t)K_DIM;      // [N,F]
    float* wout = (float*)d_out + N * (size_t)(K_DIM + F_INDIM);

    hipMemsetAsync(degF, 0, N * sizeof(int), stream);
    hipMemsetAsync(degS, 0, N * sizeof(int), stream);

    gemm1_kernel<<<N_NODES / 16, 256, 0, stream>>>(X, Wl1, Wr1, xl1, xr1);

    hist_kernel<<<(E_EDGES + 255) / 256, 256, 0, stream>>>(dstF, rowS, degF, degS);
    scan1_kernel<<<SCAN_BLOCKS, 256, 0, stream>>>(degF, degS, bsF, bsS);
    scan2_kernel<<<1, 64, 0, stream>>>(bsF, bsS);
    scan3_kernel<<<SCAN_BLOCKS, 256, 0, stream>>>(degF, degS, bsF, bsS, offF, offS, curF, curS);
    fill_kernel<<<(E_EDGES + 255) / 256, 256, 0, stream>>>(srcF, dstF, colS, rowS,
                                                           curF, curS, csrF, csrS);

    agg1_kernel<<<N_NODES / 4, 256, 0, stream>>>(offF, csrF, xl1, xr1, att1, b1,
                                                 Wl2, Wr2, xl2, xr2);
    agg2_kernel<<<(N_NODES * K_DIM + 255) / 256, 256, 0, stream>>>(offF, csrF, xl2, xr2,
                                                                   att2, b2, Z);
    sagg_kernel<<<(N_NODES * K_DIM + 255) / 256, 256, 0, stream>>>(offS, csrS, Z, Zc);
    final_kernel<<<N_NODES, 256, 0, stream>>>(Z, Zc, M, ew, out2, wout);
}

// Round 4
// 418.188 us; speedup vs baseline: 2.0500x; 1.0885x over previous
//
#include <hip/hip_runtime.h>
#include <math.h>

#define N_NODES 50000
#define E_EDGES 800000
#define F_INDIM 256
#define H_DIM   64
#define K_DIM   32
#define NEG_SLOPE 0.2f
#define SCAN_BLOCKS 196          // 196*256 = 50176 >= 50000
#define NXCD 8
#define RANGE_N 6250             // N_NODES / NXCD
#define FILL_WGPG 64             // workgroups per partition group
#define FILL_SLICE (E_EDGES / FILL_WGPG)   // 12500

// ---- DPP-based partial butterfly helpers (VALU pipe, not DS) ----
template<int CTRL>
__device__ __forceinline__ float dpp_xadd(float v) {
    int x = __builtin_amdgcn_update_dpp(0, __float_as_int(v), CTRL, 0xF, 0xF, true);
    return v + __int_as_float(x);
}
template<int CTRL>
__device__ __forceinline__ float dpp_xmax(float v) {
    int x = __builtin_amdgcn_update_dpp(0, __float_as_int(v), CTRL, 0xF, 0xF, true);
    return fmaxf(v, __int_as_float(x));
}
__device__ __forceinline__ float red_sum64(float v) {
    v = dpp_xadd<0xB1>(v); v = dpp_xadd<0x4E>(v);
    v = dpp_xadd<0x141>(v); v = dpp_xadd<0x140>(v);
    v += __shfl_xor(v, 16, 64);
    v += __shfl_xor(v, 32, 64);
    return v;
}
__device__ __forceinline__ float red_sum32(float v) {
    v = dpp_xadd<0xB1>(v); v = dpp_xadd<0x4E>(v);
    v = dpp_xadd<0x141>(v); v = dpp_xadd<0x140>(v);
    v += __shfl_xor(v, 16, 64);
    return v;
}
__device__ __forceinline__ float red_max32(float v) {
    v = dpp_xmax<0xB1>(v); v = dpp_xmax<0x4E>(v);
    v = dpp_xmax<0x141>(v); v = dpp_xmax<0x140>(v);
    v = fmaxf(v, __shfl_xor(v, 16, 64));
    return v;
}

// ---- xl = X@Wl1, xr = X@Wr1 fused.  16 nodes x 128 outputs per block ----
__global__ __launch_bounds__(256) void gemm1_kernel(
        const float* __restrict__ X, const float* __restrict__ Wl,
        const float* __restrict__ Wr, float* __restrict__ xl, float* __restrict__ xr) {
    __shared__ float xs[16][F_INDIM];          // 16 KB
    const int m0 = blockIdx.x * 16;
    const int tid = threadIdx.x;
    const float* src = X + (size_t)m0 * F_INDIM;
    for (int i = tid; i < 16 * F_INDIM; i += 256)
        xs[i >> 8][i & 255] = src[i];
    __syncthreads();
    const int tx = tid & 127;                  // output col 0..127
    const int ty = tid >> 7;                   // 0..1
    const float* W = (tx < H_DIM) ? Wl : Wr;
    const int col = tx & 63;
    float acc[8];
#pragma unroll
    for (int i = 0; i < 8; ++i) acc[i] = 0.f;
    for (int k = 0; k < F_INDIM; ++k) {
        float wv = W[k * H_DIM + col];
#pragma unroll
        for (int i = 0; i < 8; ++i) acc[i] += xs[ty + 2 * i][k] * wv;
    }
    float* out = (tx < H_DIM) ? xl : xr;
#pragma unroll
    for (int i = 0; i < 8; ++i)
        out[(size_t)(m0 + ty + 2 * i) * H_DIM + col] = acc[i];
}

// ---- XCD-partitioned degree histogram.  wg%16: 0-7 feat range, 8-15 spatial ----
__global__ __launch_bounds__(256) void phist_kernel(
        const int* __restrict__ dstF, const int* __restrict__ rowS,
        int* __restrict__ degF, int* __restrict__ degS) {
    const int wg = blockIdx.x;
    const int g  = wg & 15;
    const int j  = wg >> 4;
    const int e0 = j * FILL_SLICE, e1 = e0 + FILL_SLICE;
    if (g < NXCD) {
        const int base = g * RANGE_N;
        for (int e = e0 + (int)threadIdx.x; e < e1; e += 256) {
            int d = __builtin_nontemporal_load(&dstF[e]);
            if ((unsigned)(d - base) < RANGE_N) atomicAdd(&degF[d], 1);
        }
    } else {
        const int base = (g - NXCD) * RANGE_N;
        for (int e = e0 + (int)threadIdx.x; e < e1; e += 256) {
            int d = __builtin_nontemporal_load(&rowS[e]);
            if ((unsigned)(d - base) < RANGE_N) atomicAdd(&degS[d], 1);
        }
    }
}

// ---- scan stage 1: per-block sums ----
__global__ __launch_bounds__(256) void scan1_kernel(
        const int* __restrict__ degF, const int* __restrict__ degS,
        int* __restrict__ bsF, int* __restrict__ bsS) {
    __shared__ int sF[256], sS[256];
    const int tid = threadIdx.x;
    const int i = blockIdx.x * 256 + tid;
    sF[tid] = (i < N_NODES) ? degF[i] : 0;
    sS[tid] = (i < N_NODES) ? degS[i] : 0;
    __syncthreads();
    for (int s = 128; s > 0; s >>= 1) {
        if (tid < s) { sF[tid] += sF[tid + s]; sS[tid] += sS[tid + s]; }
        __syncthreads();
    }
    if (tid == 0) { bsF[blockIdx.x] = sF[0]; bsS[blockIdx.x] = sS[0]; }
}

// ---- scan stage 2: serial exclusive scan of block sums (196 values) ----
__global__ void scan2_kernel(int* __restrict__ bsF, int* __restrict__ bsS) {
    if (threadIdx.x == 0) {
        int run = 0;
        for (int j = 0; j < SCAN_BLOCKS; ++j) { int t = bsF[j]; bsF[j] = run; run += t; }
    } else if (threadIdx.x == 1) {
        int run = 0;
        for (int j = 0; j < SCAN_BLOCKS; ++j) { int t = bsS[j]; bsS[j] = run; run += t; }
    }
}

// ---- scan stage 3: per-block exclusive scan + base; writes offsets & cursors ----
__global__ __launch_bounds__(256) void scan3_kernel(
        const int* __restrict__ degF, const int* __restrict__ degS,
        const int* __restrict__ bsF, const int* __restrict__ bsS,
        int* __restrict__ offF, int* __restrict__ offS,
        int* __restrict__ curF, int* __restrict__ curS) {
    __shared__ int sF[256], sS[256];
    const int tid = threadIdx.x;
    const int i = blockIdx.x * 256 + tid;
    const int vF = (i < N_NODES) ? degF[i] : 0;
    const int vS = (i < N_NODES) ? degS[i] : 0;
    sF[tid] = vF; sS[tid] = vS;
    __syncthreads();
    for (int d = 1; d < 256; d <<= 1) {
        int aF = (tid >= d) ? sF[tid - d] : 0;
        int aS = (tid >= d) ? sS[tid - d] : 0;
        __syncthreads();
        sF[tid] += aF; sS[tid] += aS;
        __syncthreads();
    }
    if (i < N_NODES) {
        int oF = bsF[blockIdx.x] + sF[tid] - vF;   // exclusive
        int oS = bsS[blockIdx.x] + sS[tid] - vS;
        offF[i] = oF; curF[i] = oF;
        offS[i] = oS; curS[i] = oS;
    }
    if (i == N_NODES - 1) { offF[N_NODES] = E_EDGES; offS[N_NODES] = E_EDGES; }
}

// ---- XCD-partitioned CSR fill: writes land in the local XCD's L2 ----
__global__ __launch_bounds__(256) void pfill_kernel(
        const int* __restrict__ srcF, const int* __restrict__ dstF,
        const int* __restrict__ colS, const int* __restrict__ rowS,
        int* __restrict__ curF, int* __restrict__ curS,
        int* __restrict__ csrF, int* __restrict__ csrS) {
    const int wg = blockIdx.x;
    const int g  = wg & 15;
    const int j  = wg >> 4;
    const int e0 = j * FILL_SLICE, e1 = e0 + FILL_SLICE;
    if (g < NXCD) {
        const int base = g * RANGE_N;
        for (int e = e0 + (int)threadIdx.x; e < e1; e += 256) {
            int d = __builtin_nontemporal_load(&dstF[e]);
            if ((unsigned)(d - base) < RANGE_N) {
                int s = __builtin_nontemporal_load(&srcF[e]);
                int p = atomicAdd(&curF[d], 1);
                csrF[p] = s;
            }
        }
    } else {
        const int base = (g - NXCD) * RANGE_N;
        for (int e = e0 + (int)threadIdx.x; e < e1; e += 256) {
            int d = __builtin_nontemporal_load(&rowS[e]);
            if ((unsigned)(d - base) < RANGE_N) {
                int c = __builtin_nontemporal_load(&colS[e]);
                int q = atomicAdd(&curS[d], 1);
                csrS[q] = c;
            }
        }
    }
}

// ---- layer1: per-node online-softmax aggregation + ELU + h@[Wl2|Wr2] ----
// one 64-lane wave per node, 4 nodes per block, 8 edges per iteration
__global__ __launch_bounds__(256) void agg1_kernel(
        const int* __restrict__ offF, const int* __restrict__ csrF,
        const float* __restrict__ xl, const float* __restrict__ xr,
        const float* __restrict__ att1, const float* __restrict__ b1,
        const float* __restrict__ Wl2, const float* __restrict__ Wr2,
        float* __restrict__ xl2, float* __restrict__ xr2) {
    __shared__ float hs[4][H_DIM];
    const int wid  = threadIdx.x >> 6;
    const int lane = threadIdx.x & 63;
    const int n = blockIdx.x * 4 + wid;
    const float xrv  = xr[(size_t)n * H_DIM + lane];
    const float attv = att1[lane];
    const int start = __builtin_amdgcn_readfirstlane(offF[n]);
    const int endi  = __builtin_amdgcn_readfirstlane(offF[n + 1]);
    const int cnt = endi - start + 1;          // + self loop (message cnt-1 is src=n)
    float m = -1e30f, den = 0.f, acc = 0.f;
    int srcs[8];
#pragma unroll
    for (int j = 0; j < 8; ++j) srcs[j] = (j < cnt - 1) ? csrF[start + j] : n;
    for (int t0 = 0; t0 < cnt; t0 += 8) {
        float xc[8];
#pragma unroll
        for (int j = 0; j < 8; ++j) xc[j] = xl[(size_t)srcs[j] * H_DIM + lane];
        int nsrcs[8];
#pragma unroll
        for (int j = 0; j < 8; ++j) {
            int t = t0 + 8 + j;
            nsrcs[j] = (t < cnt - 1) ? csrF[start + t] : n;
        }
        float v[8];
#pragma unroll
        for (int j = 0; j < 8; ++j) {
            float a = xc[j] + xrv;
            a = a > 0.f ? a : NEG_SLOPE * a;
            v[j] = a * attv;
        }
#pragma unroll
        for (int j = 0; j < 8; ++j) v[j] = red_sum64(v[j]);
        float vmax = -1e30f;
#pragma unroll
        for (int j = 0; j < 8; ++j) {
            if (t0 + j >= cnt) v[j] = -1e30f;
            vmax = fmaxf(vmax, v[j]);
        }
        const float mn = fmaxf(m, vmax);
        const float sc = __expf(m - mn);       // underflows to 0 on first chunk
        acc *= sc; den *= sc;
#pragma unroll
        for (int j = 0; j < 8; ++j) {
            const float p = __expf(v[j] - mn); // 0 for masked slots
            acc += p * xc[j];
            den += p;
        }
        m = mn;
#pragma unroll
        for (int j = 0; j < 8; ++j) srcs[j] = nsrcs[j];
    }
    float h = acc / den + b1[lane];
    h = h > 0.f ? h : expm1f(h);                // ELU
    hs[wid][lane] = h;
    __syncthreads();
    const float* W = (lane < K_DIM) ? Wl2 : Wr2;
    const int col = lane & 31;
    float s = 0.f;
#pragma unroll
    for (int k = 0; k < H_DIM; ++k) s += hs[wid][k] * W[k * K_DIM + col];
    float* o = (lane < K_DIM) ? xl2 : xr2;
    o[(size_t)n * K_DIM + col] = s;
}

// ---- layer2: per-node online-softmax aggregation + bias + row softmax -> Z ----
__global__ __launch_bounds__(256) void agg2_kernel(
        const int* __restrict__ offF, const int* __restrict__ csrF,
        const float* __restrict__ xl2, const float* __restrict__ xr2,
        const float* __restrict__ att2, const float* __restrict__ b2,
        float* __restrict__ Z) {
    const int t = blockIdx.x * 256 + threadIdx.x;
    const int n = t >> 5;
    const int sub = t & 31;
    if (n >= N_NODES) return;
    const float xrv  = xr2[(size_t)n * K_DIM + sub];
    const float attv = att2[sub];
    const int start = offF[n], endi = offF[n + 1];
    const int cnt = endi - start + 1;
    float m = -1e30f, den = 0.f, acc = 0.f;
    int srcs[8];
#pragma unroll
    for (int j = 0; j < 8; ++j) srcs[j] = (j < cnt - 1) ? csrF[start + j] : n;
    for (int t0 = 0; t0 < cnt; t0 += 8) {
        float xc[8];
#pragma unroll
        for (int j = 0; j < 8; ++j) xc[j] = xl2[(size_t)srcs[j] * K_DIM + sub];
        int nsrcs[8];
#pragma unroll
        for (int j = 0; j < 8; ++j) {
            int tt = t0 + 8 + j;
            nsrcs[j] = (tt < cnt - 1) ? csrF[start + tt] : n;
        }
        float v[8];
#pragma unroll
        for (int j = 0; j < 8; ++j) {
            float a = xc[j] + xrv;
            a = a > 0.f ? a : NEG_SLOPE * a;
            v[j] = a * attv;
        }
#pragma unroll
        for (int j = 0; j < 8; ++j) v[j] = red_sum32(v[j]);
        float vmax = -1e30f;
#pragma unroll
        for (int j = 0; j < 8; ++j) {
            if (t0 + j >= cnt) v[j] = -1e30f;
            vmax = fmaxf(vmax, v[j]);
        }
        const float mn = fmaxf(m, vmax);
        const float sc = __expf(m - mn);
        acc *= sc; den *= sc;
#pragma unroll
        for (int j = 0; j < 8; ++j) {
            const float p = __expf(v[j] - mn);
            acc += p * xc[j];
            den += p;
        }
        m = mn;
#pragma unroll
        for (int j = 0; j < 8; ++j) srcs[j] = nsrcs[j];
    }
    float z = acc / den + b2[sub];
    float mx = red_max32(z);
    float e = __expf(z - mx);
    float ssum = red_sum32(e);
    Z[(size_t)n * K_DIM + sub] = e / ssum;
}

// ---- spatial contamination (gather side): Zc[n] = sum_{e: row=n} Z[col_e] ----
__global__ __launch_bounds__(256) void sagg_kernel(
        const int* __restrict__ offS, const int* __restrict__ csrS,
        const float* __restrict__ Z, float* __restrict__ Zc) {
    const int t = blockIdx.x * 256 + threadIdx.x;
    const int n = t >> 5;
    const int sub = t & 31;
    if (n >= N_NODES) return;
    const int start = offS[n], endi = offS[n + 1];
    float acc = 0.f;
    for (int t0 = start; t0 < endi; t0 += 8) {
        float val[8];
#pragma unroll
        for (int j = 0; j < 8; ++j) {
            int tt = t0 + j;
            int c = csrS[tt < endi ? tt : (endi - 1)];
            val[j] = Z[(size_t)c * K_DIM + sub];
        }
#pragma unroll
        for (int j = 0; j < 8; ++j)
            acc += (t0 + j < endi) ? val[j] : 0.f;
    }
    Zc[(size_t)n * K_DIM + sub] = acc;
}

// ---- out2 = (Z + w*Zc) @ relu(M); one node per 256-thread block ----
__global__ __launch_bounds__(256) void final_kernel(
        const float* __restrict__ Z, const float* __restrict__ Zc,
        const float* __restrict__ M, const float* __restrict__ edge_w,
        float* __restrict__ out2, float* __restrict__ wout) {
    __shared__ float zs[K_DIM];
    const int n = blockIdx.x;
    const int tid = threadIdx.x;
    const float w = 1.f / (1.f + __expf(-edge_w[0]));
    if (tid < K_DIM)
        zs[tid] = Z[(size_t)n * K_DIM + tid] + w * Zc[(size_t)n * K_DIM + tid];
    __syncthreads();
    float acc = 0.f;
#pragma unroll
    for (int k = 0; k < K_DIM; ++k)
        acc += zs[k] * fmaxf(M[k * F_INDIM + tid], 0.f);
    out2[(size_t)n * F_INDIM + tid] = acc;
    if (n == 0 && tid == 0) wout[0] = w;
}

extern "C" void kernel_launch(void* const* d_in, const int* in_sizes, int n_in,
                              void* d_out, int out_size, void* d_ws, size_t ws_size,
                              hipStream_t stream) {
    const float* X    = (const float*)d_in[0];
    const int*   eif  = (const int*)d_in[1];
    const int*   eis  = (const int*)d_in[2];
    const float* Wl1  = (const float*)d_in[3];
    const float* Wr1  = (const float*)d_in[4];
    const float* att1 = (const float*)d_in[5];
    const float* b1   = (const float*)d_in[6];
    const float* Wl2  = (const float*)d_in[7];
    const float* Wr2  = (const float*)d_in[8];
    const float* att2 = (const float*)d_in[9];
    const float* b2   = (const float*)d_in[10];
    const float* M    = (const float*)d_in[11];
    const float* ew   = (const float*)d_in[12];

    const int* srcF = eif;               // feat src
    const int* dstF = eif + E_EDGES;     // feat dst
    const int* rowS = eis;               // spatial row (segment target)
    const int* colS = eis + E_EDGES;     // spatial col (gather source)

    const size_t N = N_NODES;
    char* ws = (char*)d_ws;
    size_t off = 0;
    auto alloc = [&](size_t bytes) { char* p = ws + off; off += (bytes + 255) & ~(size_t)255; return p; };

    float* xl1  = (float*)alloc(N * H_DIM * sizeof(float));
    float* xr1  = (float*)alloc(N * H_DIM * sizeof(float));
    float* xl2  = (float*)alloc(N * K_DIM * sizeof(float));
    float* xr2  = (float*)alloc(N * K_DIM * sizeof(float));
    int*   degF = (int*)alloc(N * sizeof(int));
    int*   degS = (int*)alloc(N * sizeof(int));
    int*   offF = (int*)alloc((N + 1) * sizeof(int));
    int*   offS = (int*)alloc((N + 1) * sizeof(int));
    int*   curF = (int*)alloc(N * sizeof(int));
    int*   curS = (int*)alloc(N * sizeof(int));
    int*   bsF  = (int*)alloc(SCAN_BLOCKS * sizeof(int));
    int*   bsS  = (int*)alloc(SCAN_BLOCKS * sizeof(int));
    int*   csrF = (int*)alloc((size_t)E_EDGES * sizeof(int));
    int*   csrS = (int*)alloc((size_t)E_EDGES * sizeof(int));
    float* Zc   = (float*)alloc(N * K_DIM * sizeof(float));

    float* Z    = (float*)d_out;                          // [N,K]
    float* out2 = (float*)d_out + N * (size_t)K_DIM;      // [N,F]
    float* wout = (float*)d_out + N * (size_t)(K_DIM + F_INDIM);

    hipMemsetAsync(degF, 0, N * sizeof(int), stream);
    hipMemsetAsync(degS, 0, N * sizeof(int), stream);

    gemm1_kernel<<<N_NODES / 16, 256, 0, stream>>>(X, Wl1, Wr1, xl1, xr1);

    phist_kernel<<<16 * FILL_WGPG, 256, 0, stream>>>(dstF, rowS, degF, degS);
    scan1_kernel<<<SCAN_BLOCKS, 256, 0, stream>>>(degF, degS, bsF, bsS);
    scan2_kernel<<<1, 64, 0, stream>>>(bsF, bsS);
    scan3_kernel<<<SCAN_BLOCKS, 256, 0, stream>>>(degF, degS, bsF, bsS, offF, offS, curF, curS);
    pfill_kernel<<<16 * FILL_WGPG, 256, 0, stream>>>(srcF, dstF, colS, rowS,
                                                     curF, curS, csrF, csrS);

    agg1_kernel<<<N_NODES / 4, 256, 0, stream>>>(offF, csrF, xl1, xr1, att1, b1,
                                                 Wl2, Wr2, xl2, xr2);
    agg2_kernel<<<(N_NODES * K_DIM + 255) / 256, 256, 0, stream>>>(offF, csrF, xl2, xr2,
                                                                   att2, b2, Z);
    sagg_kernel<<<(N_NODES * K_DIM + 255) / 256, 256, 0, stream>>>(offS, csrS, Z, Zc);
    final_kernel<<<N_NODES, 256, 0, stream>>>(Z, Zc, M, ew, out2, wout);
}

// Round 5
// 382.043 us; speedup vs baseline: 2.2440x; 1.0946x over previous
//
#include <hip/hip_runtime.h>
#include <math.h>

#define N_NODES 50000
#define E_EDGES 800000
#define F_INDIM 256
#define H_DIM   64
#define K_DIM   32
#define NEG_SLOPE 0.2f
#define SCAN_BLOCKS 196          // 196*256 = 50176 >= 50000
#define NXCD 8
#define RANGE_N 6250             // N_NODES / NXCD
#define FILL_WGPG 64             // workgroups per partition group
#define FILL_SLICE (E_EDGES / FILL_WGPG)   // 12500

typedef short short8v __attribute__((ext_vector_type(8)));
typedef unsigned short us8 __attribute__((ext_vector_type(8)));
typedef float f32x4 __attribute__((ext_vector_type(4)));

// ---- bf16 helpers (RNE) ----
__device__ __forceinline__ unsigned short f2bf(float f) {
    unsigned u = __float_as_uint(f);
    unsigned r = (u + 0x7FFFu + ((u >> 16) & 1u)) >> 16;
    return (unsigned short)r;
}
__device__ __forceinline__ float bf2f(unsigned short h) {
    return __uint_as_float(((unsigned)h) << 16);
}

// ---- DPP-based partial butterfly helpers (VALU pipe, not DS) ----
template<int CTRL>
__device__ __forceinline__ float dpp_xadd(float v) {
    int x = __builtin_amdgcn_update_dpp(0, __float_as_int(v), CTRL, 0xF, 0xF, true);
    return v + __int_as_float(x);
}
template<int CTRL>
__device__ __forceinline__ float dpp_xmax(float v) {
    int x = __builtin_amdgcn_update_dpp(0, __float_as_int(v), CTRL, 0xF, 0xF, true);
    return fmaxf(v, __int_as_float(x));
}
__device__ __forceinline__ float red_sum64(float v) {
    v = dpp_xadd<0xB1>(v); v = dpp_xadd<0x4E>(v);
    v = dpp_xadd<0x141>(v); v = dpp_xadd<0x140>(v);
    v += __shfl_xor(v, 16, 64);
    v += __shfl_xor(v, 32, 64);
    return v;
}
__device__ __forceinline__ float red_sum32(float v) {
    v = dpp_xadd<0xB1>(v); v = dpp_xadd<0x4E>(v);
    v = dpp_xadd<0x141>(v); v = dpp_xadd<0x140>(v);
    v += __shfl_xor(v, 16, 64);
    return v;
}
__device__ __forceinline__ float red_max32(float v) {
    v = dpp_xmax<0xB1>(v); v = dpp_xmax<0x4E>(v);
    v = dpp_xmax<0x141>(v); v = dpp_xmax<0x140>(v);
    v = fmaxf(v, __shfl_xor(v, 16, 64));
    return v;
}

// ---- pre-pack [Wl1|Wr1] (fp32 [256][64] each) into MFMA B-fragment order,
//      hi/lo bf16 split.  4096 threads: t = (ct*8+ks)*64 + lane ----
__global__ __launch_bounds__(256) void wfrag_kernel(
        const float* __restrict__ Wl, const float* __restrict__ Wr,
        unsigned short* __restrict__ Bh, unsigned short* __restrict__ Bl) {
    const int t = blockIdx.x * 256 + threadIdx.x;
    if (t >= 4096) return;
    const int lane = t & 63;
    const int ks = (t >> 6) & 7;
    const int ct = t >> 9;
    const int n = ct * 16 + (lane & 15);       // output col 0..127
    const int kbase = ks * 32 + (lane >> 4) * 8;
    const float* W = (n < H_DIM) ? Wl : Wr;
    const int col = n & 63;
#pragma unroll
    for (int e = 0; e < 8; ++e) {
        float w = W[(size_t)(kbase + e) * H_DIM + col];
        unsigned short hi = f2bf(w);
        unsigned short lo = f2bf(w - bf2f(hi));
        Bh[(size_t)t * 8 + e] = hi;
        Bl[(size_t)t * 8 + e] = lo;
    }
}

// ---- MFMA gemm1: [xl|xr] = X @ [Wl1|Wr1] via bf16 hi/lo split ----
// block = 4 waves; wave w owns rows [blk*64+w*16, +16) x 128 cols
__global__ __launch_bounds__(256) void gemm1_mfma_kernel(
        const float* __restrict__ X,
        const unsigned short* __restrict__ Bh, const unsigned short* __restrict__ Bl,
        float* __restrict__ xl, float* __restrict__ xr) {
    const int wv = threadIdx.x >> 6;
    const int lane = threadIdx.x & 63;
    const int m0 = blockIdx.x * 64 + wv * 16;
    const int r = lane & 15;
    const int g = lane >> 4;
    int arow = m0 + r;
    if (arow > N_NODES - 1) arow = N_NODES - 1;      // clamp (stores guarded)
    const float* xrow = X + (size_t)arow * F_INDIM + g * 8;

    f32x4 acc[8];
#pragma unroll
    for (int c = 0; c < 8; ++c) acc[c] = (f32x4){0.f, 0.f, 0.f, 0.f};

    for (int ks = 0; ks < 8; ++ks) {
        const float4 f0 = *(const float4*)(xrow + ks * 32);
        const float4 f1 = *(const float4*)(xrow + ks * 32 + 4);
        float f[8] = {f0.x, f0.y, f0.z, f0.w, f1.x, f1.y, f1.z, f1.w};
        union { us8 u; short8v s; } Ah, Al;
#pragma unroll
        for (int j = 0; j < 8; ++j) {
            unsigned short hi = f2bf(f[j]);
            Ah.u[j] = hi;
            Al.u[j] = f2bf(f[j] - bf2f(hi));
        }
        union { us8 u; short8v s; } bh[8], bl[8];
#pragma unroll
        for (int ct = 0; ct < 8; ++ct) {
            const size_t fo = ((size_t)(ct * 8 + ks) * 64 + lane) * 8;
            bh[ct].u = *(const us8*)(Bh + fo);
            bl[ct].u = *(const us8*)(Bl + fo);
        }
#pragma unroll
        for (int ct = 0; ct < 8; ++ct)
            acc[ct] = __builtin_amdgcn_mfma_f32_16x16x32_bf16(Ah.s, bh[ct].s, acc[ct], 0, 0, 0);
#pragma unroll
        for (int ct = 0; ct < 8; ++ct)
            acc[ct] = __builtin_amdgcn_mfma_f32_16x16x32_bf16(Ah.s, bl[ct].s, acc[ct], 0, 0, 0);
#pragma unroll
        for (int ct = 0; ct < 8; ++ct)
            acc[ct] = __builtin_amdgcn_mfma_f32_16x16x32_bf16(Al.s, bh[ct].s, acc[ct], 0, 0, 0);
    }
    // D layout: col = lane&15 (=r), row = g*4 + i
#pragma unroll
    for (int ct = 0; ct < 8; ++ct) {
        const int n = ct * 16 + r;
        float* out = (n < H_DIM) ? xl : xr;
        const int col = n & 63;
#pragma unroll
        for (int i = 0; i < 4; ++i) {
            const int rr = m0 + g * 4 + i;
            if (rr < N_NODES) out[(size_t)rr * H_DIM + col] = acc[ct][i];
        }
    }
}

// ---- XCD-partitioned degree histogram.  wg%16: 0-7 feat range, 8-15 spatial ----
__global__ __launch_bounds__(256) void phist_kernel(
        const int* __restrict__ dstF, const int* __restrict__ rowS,
        int* __restrict__ degF, int* __restrict__ degS) {
    const int wg = blockIdx.x;
    const int g  = wg & 15;
    const int j  = wg >> 4;
    const int e0 = j * FILL_SLICE, e1 = e0 + FILL_SLICE;
    if (g < NXCD) {
        const int base = g * RANGE_N;
        for (int e = e0 + (int)threadIdx.x; e < e1; e += 256) {
            int d = __builtin_nontemporal_load(&dstF[e]);
            if ((unsigned)(d - base) < RANGE_N) atomicAdd(&degF[d], 1);
        }
    } else {
        const int base = (g - NXCD) * RANGE_N;
        for (int e = e0 + (int)threadIdx.x; e < e1; e += 256) {
            int d = __builtin_nontemporal_load(&rowS[e]);
            if ((unsigned)(d - base) < RANGE_N) atomicAdd(&degS[d], 1);
        }
    }
}

// ---- scan stage 1: per-block sums ----
__global__ __launch_bounds__(256) void scan1_kernel(
        const int* __restrict__ degF, const int* __restrict__ degS,
        int* __restrict__ bsF, int* __restrict__ bsS) {
    __shared__ int sF[256], sS[256];
    const int tid = threadIdx.x;
    const int i = blockIdx.x * 256 + tid;
    sF[tid] = (i < N_NODES) ? degF[i] : 0;
    sS[tid] = (i < N_NODES) ? degS[i] : 0;
    __syncthreads();
    for (int s = 128; s > 0; s >>= 1) {
        if (tid < s) { sF[tid] += sF[tid + s]; sS[tid] += sS[tid + s]; }
        __syncthreads();
    }
    if (tid == 0) { bsF[blockIdx.x] = sF[0]; bsS[blockIdx.x] = sS[0]; }
}

// ---- scan stage 2: serial exclusive scan of block sums (196 values) ----
__global__ void scan2_kernel(int* __restrict__ bsF, int* __restrict__ bsS) {
    if (threadIdx.x == 0) {
        int run = 0;
        for (int j = 0; j < SCAN_BLOCKS; ++j) { int t = bsF[j]; bsF[j] = run; run += t; }
    } else if (threadIdx.x == 1) {
        int run = 0;
        for (int j = 0; j < SCAN_BLOCKS; ++j) { int t = bsS[j]; bsS[j] = run; run += t; }
    }
}

// ---- scan stage 3: per-block exclusive scan + base; writes offsets & cursors ----
__global__ __launch_bounds__(256) void scan3_kernel(
        const int* __restrict__ degF, const int* __restrict__ degS,
        const int* __restrict__ bsF, const int* __restrict__ bsS,
        int* __restrict__ offF, int* __restrict__ offS,
        int* __restrict__ curF, int* __restrict__ curS) {
    __shared__ int sF[256], sS[256];
    const int tid = threadIdx.x;
    const int i = blockIdx.x * 256 + tid;
    const int vF = (i < N_NODES) ? degF[i] : 0;
    const int vS = (i < N_NODES) ? degS[i] : 0;
    sF[tid] = vF; sS[tid] = vS;
    __syncthreads();
    for (int d = 1; d < 256; d <<= 1) {
        int aF = (tid >= d) ? sF[tid - d] : 0;
        int aS = (tid >= d) ? sS[tid - d] : 0;
        __syncthreads();
        sF[tid] += aF; sS[tid] += aS;
        __syncthreads();
    }
    if (i < N_NODES) {
        int oF = bsF[blockIdx.x] + sF[tid] - vF;   // exclusive
        int oS = bsS[blockIdx.x] + sS[tid] - vS;
        offF[i] = oF; curF[i] = oF;
        offS[i] = oS; curS[i] = oS;
    }
    if (i == N_NODES - 1) { offF[N_NODES] = E_EDGES; offS[N_NODES] = E_EDGES; }
}

// ---- XCD-partitioned CSR fill: writes land in the local XCD's L2 ----
__global__ __launch_bounds__(256) void pfill_kernel(
        const int* __restrict__ srcF, const int* __restrict__ dstF,
        const int* __restrict__ colS, const int* __restrict__ rowS,
        int* __restrict__ curF, int* __restrict__ curS,
        int* __restrict__ csrF, int* __restrict__ csrS) {
    const int wg = blockIdx.x;
    const int g  = wg & 15;
    const int j  = wg >> 4;
    const int e0 = j * FILL_SLICE, e1 = e0 + FILL_SLICE;
    if (g < NXCD) {
        const int base = g * RANGE_N;
        for (int e = e0 + (int)threadIdx.x; e < e1; e += 256) {
            int d = __builtin_nontemporal_load(&dstF[e]);
            if ((unsigned)(d - base) < RANGE_N) {
                int s = __builtin_nontemporal_load(&srcF[e]);
                int p = atomicAdd(&curF[d], 1);
                csrF[p] = s;
            }
        }
    } else {
        const int base = (g - NXCD) * RANGE_N;
        for (int e = e0 + (int)threadIdx.x; e < e1; e += 256) {
            int d = __builtin_nontemporal_load(&rowS[e]);
            if ((unsigned)(d - base) < RANGE_N) {
                int c = __builtin_nontemporal_load(&colS[e]);
                int q = atomicAdd(&curS[d], 1);
                csrS[q] = c;
            }
        }
    }
}

// ---- layer1: per-node online-softmax aggregation + ELU + h@[Wl2|Wr2] ----
__global__ __launch_bounds__(256) void agg1_kernel(
        const int* __restrict__ offF, const int* __restrict__ csrF,
        const float* __restrict__ xl, const float* __restrict__ xr,
        const float* __restrict__ att1, const float* __restrict__ b1,
        const float* __restrict__ Wl2, const float* __restrict__ Wr2,
        float* __restrict__ xl2, float* __restrict__ xr2) {
    __shared__ float hs[4][H_DIM];
    const int wid  = threadIdx.x >> 6;
    const int lane = threadIdx.x & 63;
    const int n = blockIdx.x * 4 + wid;
    const float xrv  = xr[(size_t)n * H_DIM + lane];
    const float attv = att1[lane];
    const int start = __builtin_amdgcn_readfirstlane(offF[n]);
    const int endi  = __builtin_amdgcn_readfirstlane(offF[n + 1]);
    const int cnt = endi - start + 1;          // + self loop (message cnt-1 is src=n)
    float m = -1e30f, den = 0.f, acc = 0.f;
    int srcs[8];
#pragma unroll
    for (int j = 0; j < 8; ++j) srcs[j] = (j < cnt - 1) ? csrF[start + j] : n;
    for (int t0 = 0; t0 < cnt; t0 += 8) {
        float xc[8];
#pragma unroll
        for (int j = 0; j < 8; ++j) xc[j] = xl[(size_t)srcs[j] * H_DIM + lane];
        int nsrcs[8];
#pragma unroll
        for (int j = 0; j < 8; ++j) {
            int t = t0 + 8 + j;
            nsrcs[j] = (t < cnt - 1) ? csrF[start + t] : n;
        }
        float v[8];
#pragma unroll
        for (int j = 0; j < 8; ++j) {
            float a = xc[j] + xrv;
            a = a > 0.f ? a : NEG_SLOPE * a;
            v[j] = a * attv;
        }
#pragma unroll
        for (int j = 0; j < 8; ++j) v[j] = red_sum64(v[j]);
        float vmax = -1e30f;
#pragma unroll
        for (int j = 0; j < 8; ++j) {
            if (t0 + j >= cnt) v[j] = -1e30f;
            vmax = fmaxf(vmax, v[j]);
        }
        const float mn = fmaxf(m, vmax);
        const float sc = __expf(m - mn);       // underflows to 0 on first chunk
        acc *= sc; den *= sc;
#pragma unroll
        for (int j = 0; j < 8; ++j) {
            const float p = __expf(v[j] - mn); // 0 for masked slots
            acc += p * xc[j];
            den += p;
        }
        m = mn;
#pragma unroll
        for (int j = 0; j < 8; ++j) srcs[j] = nsrcs[j];
    }
    float h = acc / den + b1[lane];
    h = h > 0.f ? h : expm1f(h);                // ELU
    hs[wid][lane] = h;
    __syncthreads();
    const float* W = (lane < K_DIM) ? Wl2 : Wr2;
    const int col = lane & 31;
    float s = 0.f;
#pragma unroll
    for (int k = 0; k < H_DIM; ++k) s += hs[wid][k] * W[k * K_DIM + col];
    float* o = (lane < K_DIM) ? xl2 : xr2;
    o[(size_t)n * K_DIM + col] = s;
}

// ---- layer2: per-node online-softmax aggregation + bias + row softmax -> Z ----
__global__ __launch_bounds__(256) void agg2_kernel(
        const int* __restrict__ offF, const int* __restrict__ csrF,
        const float* __restrict__ xl2, const float* __restrict__ xr2,
        const float* __restrict__ att2, const float* __restrict__ b2,
        float* __restrict__ Z) {
    const int t = blockIdx.x * 256 + threadIdx.x;
    const int n = t >> 5;
    const int sub = t & 31;
    if (n >= N_NODES) return;
    const float xrv  = xr2[(size_t)n * K_DIM + sub];
    const float attv = att2[sub];
    const int start = offF[n], endi = offF[n + 1];
    const int cnt = endi - start + 1;
    float m = -1e30f, den = 0.f, acc = 0.f;
    int srcs[8];
#pragma unroll
    for (int j = 0; j < 8; ++j) srcs[j] = (j < cnt - 1) ? csrF[start + j] : n;
    for (int t0 = 0; t0 < cnt; t0 += 8) {
        float xc[8];
#pragma unroll
        for (int j = 0; j < 8; ++j) xc[j] = xl2[(size_t)srcs[j] * K_DIM + sub];
        int nsrcs[8];
#pragma unroll
        for (int j = 0; j < 8; ++j) {
            int tt = t0 + 8 + j;
            nsrcs[j] = (tt < cnt - 1) ? csrF[start + tt] : n;
        }
        float v[8];
#pragma unroll
        for (int j = 0; j < 8; ++j) {
            float a = xc[j] + xrv;
            a = a > 0.f ? a : NEG_SLOPE * a;
            v[j] = a * attv;
        }
#pragma unroll
        for (int j = 0; j < 8; ++j) v[j] = red_sum32(v[j]);
        float vmax = -1e30f;
#pragma unroll
        for (int j = 0; j < 8; ++j) {
            if (t0 + j >= cnt) v[j] = -1e30f;
            vmax = fmaxf(vmax, v[j]);
        }
        const float mn = fmaxf(m, vmax);
        const float sc = __expf(m - mn);
        acc *= sc; den *= sc;
#pragma unroll
        for (int j = 0; j < 8; ++j) {
            const float p = __expf(v[j] - mn);
            acc += p * xc[j];
            den += p;
        }
        m = mn;
#pragma unroll
        for (int j = 0; j < 8; ++j) srcs[j] = nsrcs[j];
    }
    float z = acc / den + b2[sub];
    float mx = red_max32(z);
    float e = __expf(z - mx);
    float ssum = red_sum32(e);
    Z[(size_t)n * K_DIM + sub] = e / ssum;
}

// ---- spatial contamination (gather side): Zc[n] = sum_{e: row=n} Z[col_e] ----
__global__ __launch_bounds__(256) void sagg_kernel(
        const int* __restrict__ offS, const int* __restrict__ csrS,
        const float* __restrict__ Z, float* __restrict__ Zc) {
    const int t = blockIdx.x * 256 + threadIdx.x;
    const int n = t >> 5;
    const int sub = t & 31;
    if (n >= N_NODES) return;
    const int start = offS[n], endi = offS[n + 1];
    float acc = 0.f;
    for (int t0 = start; t0 < endi; t0 += 8) {
        float val[8];
#pragma unroll
        for (int j = 0; j < 8; ++j) {
            int tt = t0 + j;
            int c = csrS[tt < endi ? tt : (endi - 1)];
            val[j] = Z[(size_t)c * K_DIM + sub];
        }
#pragma unroll
        for (int j = 0; j < 8; ++j)
            acc += (t0 + j < endi) ? val[j] : 0.f;
    }
    Zc[(size_t)n * K_DIM + sub] = acc;
}

// ---- out2 = (Z + w*Zc) @ relu(M); one node per 256-thread block ----
__global__ __launch_bounds__(256) void final_kernel(
        const float* __restrict__ Z, const float* __restrict__ Zc,
        const float* __restrict__ M, const float* __restrict__ edge_w,
        float* __restrict__ out2, float* __restrict__ wout) {
    __shared__ float zs[K_DIM];
    const int n = blockIdx.x;
    const int tid = threadIdx.x;
    const float w = 1.f / (1.f + __expf(-edge_w[0]));
    if (tid < K_DIM)
        zs[tid] = Z[(size_t)n * K_DIM + tid] + w * Zc[(size_t)n * K_DIM + tid];
    __syncthreads();
    float acc = 0.f;
#pragma unroll
    for (int k = 0; k < K_DIM; ++k)
        acc += zs[k] * fmaxf(M[k * F_INDIM + tid], 0.f);
    out2[(size_t)n * F_INDIM + tid] = acc;
    if (n == 0 && tid == 0) wout[0] = w;
}

extern "C" void kernel_launch(void* const* d_in, const int* in_sizes, int n_in,
                              void* d_out, int out_size, void* d_ws, size_t ws_size,
                              hipStream_t stream) {
    const float* X    = (const float*)d_in[0];
    const int*   eif  = (const int*)d_in[1];
    const int*   eis  = (const int*)d_in[2];
    const float* Wl1  = (const float*)d_in[3];
    const float* Wr1  = (const float*)d_in[4];
    const float* att1 = (const float*)d_in[5];
    const float* b1   = (const float*)d_in[6];
    const float* Wl2  = (const float*)d_in[7];
    const float* Wr2  = (const float*)d_in[8];
    const float* att2 = (const float*)d_in[9];
    const float* b2   = (const float*)d_in[10];
    const float* M    = (const float*)d_in[11];
    const float* ew   = (const float*)d_in[12];

    const int* srcF = eif;               // feat src
    const int* dstF = eif + E_EDGES;     // feat dst
    const int* rowS = eis;               // spatial row (segment target)
    const int* colS = eis + E_EDGES;     // spatial col (gather source)

    const size_t N = N_NODES;
    char* ws = (char*)d_ws;
    size_t off = 0;
    auto alloc = [&](size_t bytes) { char* p = ws + off; off += (bytes + 255) & ~(size_t)255; return p; };

    float* xl1  = (float*)alloc(N * H_DIM * sizeof(float));
    float* xr1  = (float*)alloc(N * H_DIM * sizeof(float));
    float* xl2  = (float*)alloc(N * K_DIM * sizeof(float));
    float* xr2  = (float*)alloc(N * K_DIM * sizeof(float));
    int*   degF = (int*)alloc(N * sizeof(int));
    int*   degS = (int*)alloc(N * sizeof(int));
    int*   offF = (int*)alloc((N + 1) * sizeof(int));
    int*   offS = (int*)alloc((N + 1) * sizeof(int));
    int*   curF = (int*)alloc(N * sizeof(int));
    int*   curS = (int*)alloc(N * sizeof(int));
    int*   bsF  = (int*)alloc(SCAN_BLOCKS * sizeof(int));
    int*   bsS  = (int*)alloc(SCAN_BLOCKS * sizeof(int));
    int*   csrF = (int*)alloc((size_t)E_EDGES * sizeof(int));
    int*   csrS = (int*)alloc((size_t)E_EDGES * sizeof(int));
    float* Zc   = (float*)alloc(N * K_DIM * sizeof(float));
    unsigned short* Bh = (unsigned short*)alloc(4096 * 8 * sizeof(unsigned short));
    unsigned short* Bl = (unsigned short*)alloc(4096 * 8 * sizeof(unsigned short));

    float* Z    = (float*)d_out;                          // [N,K]
    float* out2 = (float*)d_out + N * (size_t)K_DIM;      // [N,F]
    float* wout = (float*)d_out + N * (size_t)(K_DIM + F_INDIM);

    hipMemsetAsync(degF, 0, N * sizeof(int), stream);
    hipMemsetAsync(degS, 0, N * sizeof(int), stream);

    wfrag_kernel<<<16, 256, 0, stream>>>(Wl1, Wr1, Bh, Bl);
    gemm1_mfma_kernel<<<(N_NODES + 63) / 64, 256, 0, stream>>>(X, Bh, Bl, xl1, xr1);

    phist_kernel<<<16 * FILL_WGPG, 256, 0, stream>>>(dstF, rowS, degF, degS);
    scan1_kernel<<<SCAN_BLOCKS, 256, 0, stream>>>(degF, degS, bsF, bsS);
    scan2_kernel<<<1, 64, 0, stream>>>(bsF, bsS);
    scan3_kernel<<<SCAN_BLOCKS, 256, 0, stream>>>(degF, degS, bsF, bsS, offF, offS, curF, curS);
    pfill_kernel<<<16 * FILL_WGPG, 256, 0, stream>>>(srcF, dstF, colS, rowS,
                                                     curF, curS, csrF, csrS);

    agg1_kernel<<<N_NODES / 4, 256, 0, stream>>>(offF, csrF, xl1, xr1, att1, b1,
                                                 Wl2, Wr2, xl2, xr2);
    agg2_kernel<<<(N_NODES * K_DIM + 255) / 256, 256, 0, stream>>>(offF, csrF, xl2, xr2,
                                                                   att2, b2, Z);
    sagg_kernel<<<(N_NODES * K_DIM + 255) / 256, 256, 0, stream>>>(offS, csrS, Z, Zc);
    final_kernel<<<N_NODES, 256, 0, stream>>>(Z, Zc, M, ew, out2, wout);
}